// Round 13
// baseline (405.418 us; speedup 1.0000x reference)
//
#include <hip/hip_runtime.h>

typedef unsigned short u16;
typedef unsigned int u32;
typedef __attribute__((ext_vector_type(8))) short short8;  // 8 bf16 (4 VGPRs)
typedef __attribute__((ext_vector_type(4))) float f32x4;

constexpr int NA = 50000, NB = 50000;
constexpr int EMB = 16, HID = 64;
constexpr int NE = 800000;
constexpr int NBKT = 782;   // buckets per relation, 64 dsts each (782*64=50048)
constexpr int CAPB = 1536;  // bucket capacity: mean 1024, sd 32 -> +16 sd
constexpr int EPB = 4096;   // edges per multisplit block (196 blocks/relation)
constexpr int BPR = (NE + EPB - 1) / EPB;  // 196
constexpr int MSB = 3 * BPR;               // 588 multisplit blocks (2.3/CU tail)

#define MFMA16(a, b, c) __builtin_amdgcn_mfma_f32_16x16x32_bf16(a, b, c, 0, 0, 0)

__device__ inline u16 f2bf(float f) {  // RNE f32->bf16
  u32 b = __float_as_uint(f);
  return (u16)((b + 0x7FFFu + ((b >> 16) & 1u)) >> 16);
}
__device__ inline float bfl(u32 u) { return __uint_as_float(u << 16); }
__device__ inline float bfh(u32 u) { return __uint_as_float(u & 0xFFFF0000u); }
__device__ inline float bfs(u16 u) { return __uint_as_float((u32)u << 16); }

// ---------------- K0: tables (ROW-major T2[fdbin][col]) + weight-prep ------------
__global__ void __launch_bounds__(256) k_pre(
    const float* __restrict__ embA, const float* __restrict__ embB,
    const float* __restrict__ preWA, const float* __restrict__ preWB,
    float* __restrict__ T,
    const float* __restrict__ Wr_ba, const float* __restrict__ Wr_aa,
    const float* __restrict__ Wl_ba, const float* __restrict__ Wl_aa,
    const float* __restrict__ Wl_ab, const float* __restrict__ Wr_ab,
    const float* __restrict__ bl_ba, const float* __restrict__ bl_aa,
    const float* __restrict__ projWA, const float* __restrict__ projWB,
    const float* __restrict__ headWA, const float* __restrict__ headWB,
    const float* __restrict__ bilW_ba, const float* __restrict__ bilW_aa,
    const float* __restrict__ bilW_ab,
    u16* __restrict__ frag, float* __restrict__ bhA) {
  int blk = blockIdx.x;
  int t = threadIdx.x;

  if (blk < 128) {  // ---- tables ----
    int id = blk * 256 + t;  // 0..32767
    int type = id >> 14;
    int rem = id & 16383;
    int fdbin = rem >> 6;  // 0..255
    int col = rem & 63;    // 0..63 (lane-fast -> coalesced)
    int fd = fdbin >> 5;
    const float* emb = type ? embB : embA;
    const float* W = type ? preWB : preWA;
    const float* e = emb + fdbin * EMB;
    const float* w = W + (fd * EMB) * HID + col;
    float s = 0.f;
#pragma unroll
    for (int j = 0; j < EMB; ++j) s += e[j] * w[j * HID];
    T[id] = s;
    return;
  }

  // ---- prep ----
  int tid = (blk - 128) * 256 + t;  // 0..5631
  if (tid >= 86 * 64) {
    int i = tid - 86 * 64;
    if (i < 64) bhA[i] = 0.5f * (bl_ba[i] + bl_aa[i]);
    return;
  }
  int f = tid >> 6, lane = tid & 63;
  int nidx = lane & 15, quad = lane >> 4;
  u16* dst = frag + (size_t)f * 512 + lane * 8;
#pragma unroll
  for (int j = 0; j < 8; ++j) {
    int kq = quad * 8 + j;
    float v;
    if (f < 24) {
      int s = f >> 2, nt = f & 3, k = s * 32 + kq, c = nt * 16 + nidx;
      v = (k < 64) ? 0.5f * (Wr_ba[k * 64 + c] + Wr_aa[k * 64 + c])
          : (k < 128) ? 0.5f * Wl_ba[(k - 64) * 64 + c]
                      : 0.5f * Wl_aa[(k - 128) * 64 + c];
    } else if (f < 28) {
      int g = f - 24, k = (g >> 1) * 32 + kq, c = (g & 1) * 16 + nidx;
      v = projWA[k * 32 + c];
    } else if (f < 44) {
      int c = (f - 28) * 16 + nidx;
      v = headWA[kq * 256 + c];
    } else if (f < 46) {
      int i2 = (f - 44) * 16 + nidx;
      v = bilW_ba[i2 * 32 + kq];
    } else if (f < 48) {
      int i2 = (f - 46) * 16 + nidx;
      v = bilW_aa[i2 * 32 + kq];
    } else if (f < 64) {
      int g = f - 48, s = g >> 2, nt = g & 3, k = s * 32 + kq, c = nt * 16 + nidx;
      v = (k < 64) ? Wr_ab[k * 64 + c] : Wl_ab[(k - 64) * 64 + c];
    } else if (f < 68) {
      int g = f - 64, k = (g >> 1) * 32 + kq, c = (g & 1) * 16 + nidx;
      v = projWB[k * 32 + c];
    } else if (f < 84) {
      int c = (f - 68) * 16 + nidx;
      v = headWB[kq * 256 + c];
    } else {
      int i2 = (f - 84) * 16 + nidx;
      v = bilW_ab[i2 * 32 + kq];
    }
    dst[j] = f2bf(v);
  }
}

// ---------------- K1: fused multisplit + x0-direct (one launch) ------------------
__global__ void __launch_bounds__(256) k_msx0(
    const int* __restrict__ xA, const int* __restrict__ xB,
    const float* __restrict__ T,
    const float* __restrict__ biasA, const float* __restrict__ biasB,
    u16* __restrict__ x0A, u16* __restrict__ x0B,
    const int* __restrict__ ei_ab, const int* __restrict__ ei_ba,
    const int* __restrict__ ei_aa, int* __restrict__ gcur,
    u32* __restrict__ buckets) {
  __shared__ u32 ebuf2[EPB];   // 16KB sorted staging
  __shared__ int hist[NBKT];   // counts -> ranked-write cursor
  __shared__ int loff[NBKT];   // local exclusive prefix
  __shared__ int delta[NBKT];  // global_off - local_off per bucket
  __shared__ int scanw[256];
  int blk = blockIdx.x;
  int t = threadIdx.x;

  if (blk < MSB) {  // ---- multisplit ----
    int rel = blk / BPR;
    int lb = blk - rel * BPR;
    const int* ei = rel == 0 ? ei_ab : (rel == 1 ? ei_ba : ei_aa);
    int e0 = lb * EPB;
    int n = min(EPB, NE - e0);
    for (int i = t; i < NBKT; i += 256) hist[i] = 0;
    __syncthreads();
    // pass 1: histogram
    for (int i = t; i < n; i += 256) {
      int dstn = ei[NE + e0 + i];
      atomicAdd(&hist[dstn >> 6], 1);
    }
    __syncthreads();
    // exclusive prefix sum hist -> loff (4 entries/thread + scan over 256)
    int base4 = t * 4;
    int s = 0;
#pragma unroll
    for (int k = 0; k < 4; ++k) {
      int idx = base4 + k;
      if (idx < NBKT) s += hist[idx];
    }
    scanw[t] = s;
    __syncthreads();
    for (int off = 1; off < 256; off <<= 1) {
      int v = (t >= off) ? scanw[t - off] : 0;
      __syncthreads();
      scanw[t] += v;
      __syncthreads();
    }
    int run = (t == 0) ? 0 : scanw[t - 1];
#pragma unroll
    for (int k = 0; k < 4; ++k) {
      int idx = base4 + k;
      if (idx < NBKT) {
        loff[idx] = run;
        run += hist[idx];
      }
    }
    __syncthreads();
    // reserve global runs; hist becomes the running ranked-write cursor
    for (int i = t; i < NBKT; i += 256) {
      int c = hist[i];
      if (c > 0) {
        int g = atomicAdd(&gcur[rel * NBKT + i], c);
        delta[i] = g - loff[i];
      }
      hist[i] = loff[i];
    }
    __syncthreads();
    // pass 2a: ranked scatter into LDS, bucket id tagged in bits 22..31
    for (int i = t; i < n; i += 256) {
      int src = ei[e0 + i];
      int dstn = ei[NE + e0 + i];
      int b = dstn >> 6;
      int p = atomicAdd(&hist[b], 1);
      ebuf2[p] = ((u32)b << 22) | ((u32)src << 6) | (u32)(dstn & 63);
    }
    __syncthreads();
    // pass 2b: coalesced copy (consecutive j, same bucket -> consecutive gmem)
    for (int j = t; j < n; j += 256) {
      u32 v = ebuf2[j];
      int b = v >> 22;
      int gpos = delta[b] + j;  // = global_off + local_rank within bucket b
      if (gpos < CAPB)
        buckets[(size_t)(rel * NBKT + b) * CAPB + gpos] = v & 0x3FFFFFu;
    }
    return;
  }

  // ---- x0 direct-gather ----
  int xblk = blk - MSB;  // 0..1563
  int type = xblk >= 782;
  int lb = type ? xblk - 782 : xblk;
  const int* x = type ? xB : xA;
  const float4* Tv = (const float4*)(T + (type ? 16384 : 0));
  const float* bias = type ? biasB : biasA;
  u16* x0 = type ? x0B : x0A;
  const int N = NA;  // NA == NB

  int r = t >> 2, q = t & 3;
  int row = lb * 64 + r;
  bool valid = row < N;
  int arow = valid ? row : (N - 1);
  const int4* xp = (const int4*)(x + arow * 8);
  int4 xa = xp[0], xb = xp[1];
  int bins[8] = {xa.x, xa.y, xa.z, xa.w, xb.x, xb.y, xb.z, xb.w};
  int c0 = q * 16;
  float acc[16];
#pragma unroll
  for (int j = 0; j < 16; ++j) acc[j] = bias[c0 + j];
#pragma unroll
  for (int fd = 0; fd < 8; ++fd) {
    int base = (fd * 32 + bins[fd]) * 16 + q * 4;  // float4 index into T2 row
    float4 v0 = Tv[base], v1 = Tv[base + 1], v2 = Tv[base + 2], v3 = Tv[base + 3];
    acc[0] += v0.x;  acc[1] += v0.y;  acc[2] += v0.z;  acc[3] += v0.w;
    acc[4] += v1.x;  acc[5] += v1.y;  acc[6] += v1.z;  acc[7] += v1.w;
    acc[8] += v2.x;  acc[9] += v2.y;  acc[10] += v2.z; acc[11] += v2.w;
    acc[12] += v3.x; acc[13] += v3.y; acc[14] += v3.z; acc[15] += v3.w;
  }
  if (valid) {
    u32 p[8];
#pragma unroll
    for (int j = 0; j < 8; ++j) {
      u16 lo = f2bf(fmaxf(acc[2 * j], 0.f));
      u16 hi = f2bf(fmaxf(acc[2 * j + 1], 0.f));
      p[j] = (u32)lo | ((u32)hi << 16);
    }
    u32* o = (u32*)(x0 + (size_t)row * 64 + c0);
    *(uint4*)o = *(uint4*)&p[0];
    *((uint4*)o + 1) = *(uint4*)&p[4];
  }
}

// ---------------- K3: per-bucket counting-sort + HALF-DIM 2-pass gather-mean -----
// ONE RELATION PER LAUNCH (782 blocks, all resident): the old 2346-block grid
// had ~2048 blocks of all 3 relations resident -> per-XCD gather working set
// 12.8MB vs 4MB L2 (R2: 129MB FETCH vs 12.8MB compulsory). Per relation the
// x0 table is 6.4MB; the per-block half-dim pass loop (dims 0..31 then 32..63)
// cuts the instantaneous working set to 3.2MB -> guaranteed per-XCD L2 fit.
// Per-dim accumulation order is unchanged (dims independent) -> bit-identical.
__global__ void __launch_bounds__(256) k_meansort_rel(
    const u32* __restrict__ bkts, const int* __restrict__ cur,
    const u16* __restrict__ x0, u16* __restrict__ out) {
  __shared__ u32 ebuf[CAPB];
  __shared__ u16 csr[CAPB];
  __shared__ int dcnt[64], doff[64], wcur[64];
  int lb = blockIdx.x;  // 0..NBKT-1
  int t = threadIdx.x;
  int n = min(cur[lb], CAPB);
  const u32* bk = bkts + (size_t)lb * CAPB;
  if (t < 64) dcnt[t] = 0;
  __syncthreads();
  for (int i = t; i < n; i += 256) {
    u32 v = bk[i];
    ebuf[i] = v;
    atomicAdd(&dcnt[v & 63], 1);
  }
  __syncthreads();
  if (t == 0) {
    int s = 0;
#pragma unroll
    for (int d = 0; d < 64; ++d) {
      doff[d] = s;
      wcur[d] = s;
      s += dcnt[d];
    }
  }
  __syncthreads();
  for (int i = t; i < n; i += 256) {
    u32 v = ebuf[i];
    int p = atomicAdd(&wcur[v & 63], 1);
    csr[p] = (u16)(v >> 6);
  }
  __syncthreads();
  int lane = t & 63, w = t >> 6;
  int g = lane >> 4;            // dst sub-group 0..3 within wave
  int dim2b = (lane & 15) * 2;  // this lane's 2 dims within the half
  int base = lb * 64;
#pragma unroll
  for (int pass = 0; pass < 2; ++pass) {
    int dim2 = dim2b + pass * 32;
    for (int c = 0; c < 4; ++c) {
      int dloc = w * 16 + c * 4 + g;
      int dstn = base + dloc;
      if (dstn < 50000) {
        int off = doff[dloc], deg = dcnt[dloc];
        float a0 = 0.f, a1 = 0.f;
        int i = 0;
        for (; i + 8 <= deg; i += 8) {
          u32 v0 = *(const u32*)(x0 + (size_t)csr[off + i] * 64 + dim2);
          u32 v1 = *(const u32*)(x0 + (size_t)csr[off + i + 1] * 64 + dim2);
          u32 v2 = *(const u32*)(x0 + (size_t)csr[off + i + 2] * 64 + dim2);
          u32 v3 = *(const u32*)(x0 + (size_t)csr[off + i + 3] * 64 + dim2);
          u32 v4 = *(const u32*)(x0 + (size_t)csr[off + i + 4] * 64 + dim2);
          u32 v5 = *(const u32*)(x0 + (size_t)csr[off + i + 5] * 64 + dim2);
          u32 v6 = *(const u32*)(x0 + (size_t)csr[off + i + 6] * 64 + dim2);
          u32 v7 = *(const u32*)(x0 + (size_t)csr[off + i + 7] * 64 + dim2);
          a0 += bfl(v0) + bfl(v1) + bfl(v2) + bfl(v3) +
                bfl(v4) + bfl(v5) + bfl(v6) + bfl(v7);
          a1 += bfh(v0) + bfh(v1) + bfh(v2) + bfh(v3) +
                bfh(v4) + bfh(v5) + bfh(v6) + bfh(v7);
        }
        for (; i + 4 <= deg; i += 4) {
          u32 v0 = *(const u32*)(x0 + (size_t)csr[off + i] * 64 + dim2);
          u32 v1 = *(const u32*)(x0 + (size_t)csr[off + i + 1] * 64 + dim2);
          u32 v2 = *(const u32*)(x0 + (size_t)csr[off + i + 2] * 64 + dim2);
          u32 v3 = *(const u32*)(x0 + (size_t)csr[off + i + 3] * 64 + dim2);
          a0 += bfl(v0) + bfl(v1) + bfl(v2) + bfl(v3);
          a1 += bfh(v0) + bfh(v1) + bfh(v2) + bfh(v3);
        }
        for (; i < deg; ++i) {
          u32 v0 = *(const u32*)(x0 + (size_t)csr[off + i] * 64 + dim2);
          a0 += bfl(v0);
          a1 += bfh(v0);
        }
        float inv = deg > 0 ? 1.f / (float)deg : 0.f;
        *(u32*)(out + (size_t)dstn * 64 + dim2) =
            (u32)f2bf(a0 * inv) | ((u32)f2bf(a1 * inv) << 16);
      }
    }
  }
}

// ---------------- K4: fused MFMA node chain (A and B in one grid) ----------------
template <int NS, int NY>
__device__ __forceinline__ void node_chain(
    const u16* __restrict__ x0, const u16* __restrict__ m1, const u16* __restrict__ m2,
    const u16* __restrict__ frag, int f1, int f2, int fy, int fh,
    const float* __restrict__ hbias, const float* __restrict__ projb,
    const float* __restrict__ headb,
    float* __restrict__ zout, float* __restrict__ flout,
    u16* __restrict__ zbf, u16* __restrict__ y1bf, u16* __restrict__ y2bf,
    int rows0, int N, u16* hld, u16* zld, int lane) {
  int nidx = lane & 15, quad = lane >> 4;
  size_t r0 = (size_t)min(rows0 + nidx, N - 1);
  size_t r1 = (size_t)min(rows0 + 16 + nidx, N - 1);

  f32x4 acc[2][4];
#pragma unroll
  for (int mt = 0; mt < 2; ++mt)
#pragma unroll
    for (int nt = 0; nt < 4; ++nt) acc[mt][nt] = {0.f, 0.f, 0.f, 0.f};
  const u16* mats[3] = {x0, m1, m2};
#pragma unroll
  for (int s = 0; s < NS; ++s) {
    const u16* src = mats[s >> 1];
    int koff = (s & 1) * 32 + quad * 8;
    short8 a0 = *(const short8*)(src + r0 * 64 + koff);
    short8 a1 = *(const short8*)(src + r1 * 64 + koff);
#pragma unroll
    for (int nt = 0; nt < 4; ++nt) {
      short8 b = *(const short8*)(frag + (size_t)(f1 + s * 4 + nt) * 512 + lane * 8);
      acc[0][nt] = MFMA16(a0, b, acc[0][nt]);
      acc[1][nt] = MFMA16(a1, b, acc[1][nt]);
    }
  }
#pragma unroll
  for (int mt = 0; mt < 2; ++mt)
#pragma unroll
    for (int nt = 0; nt < 4; ++nt) {
      int col = nt * 16 + nidx;
      float bb = hbias[col];
#pragma unroll
      for (int r2 = 0; r2 < 4; ++r2)
        hld[(mt * 16 + quad * 4 + r2) * 72 + col] = f2bf(acc[mt][nt][r2] + bb);
    }

  f32x4 zacc[2][2];
#pragma unroll
  for (int mt = 0; mt < 2; ++mt)
#pragma unroll
    for (int nt = 0; nt < 2; ++nt) zacc[mt][nt] = {0.f, 0.f, 0.f, 0.f};
#pragma unroll
  for (int s = 0; s < 2; ++s) {
    short8 a0 = *(const short8*)(hld + nidx * 72 + s * 32 + quad * 8);
    short8 a1 = *(const short8*)(hld + (16 + nidx) * 72 + s * 32 + quad * 8);
#pragma unroll
    for (int nt = 0; nt < 2; ++nt) {
      short8 b = *(const short8*)(frag + (size_t)(f2 + s * 2 + nt) * 512 + lane * 8);
      zacc[0][nt] = MFMA16(a0, b, zacc[0][nt]);
      zacc[1][nt] = MFMA16(a1, b, zacc[1][nt]);
    }
  }
#pragma unroll
  for (int mt = 0; mt < 2; ++mt)
#pragma unroll
    for (int nt = 0; nt < 2; ++nt) {
      int col = nt * 16 + nidx;
      float pb = projb[col];
#pragma unroll
      for (int r2 = 0; r2 < 4; ++r2) {
        int rl = mt * 16 + quad * 4 + r2;
        float zv = fmaxf(zacc[mt][nt][r2] + pb, 0.f);
        zld[rl * 40 + col] = f2bf(zv);
        int grow = rows0 + rl;
        if (grow < N) zout[(size_t)grow * 32 + col] = zv;
      }
    }
  {  // coalesced bf16 z store (2 lanes per row)
    int rl = lane >> 1, hf = lane & 1;
    int grow = rows0 + rl;
    if (grow < N) {
      short8 v0 = *(const short8*)(zld + rl * 40 + hf * 16);
      short8 v1 = *(const short8*)(zld + rl * 40 + hf * 16 + 8);
      *(short8*)(zbf + (size_t)grow * 32 + hf * 16) = v0;
      *(short8*)(zbf + (size_t)grow * 32 + hf * 16 + 8) = v1;
    }
  }

  short8 az0 = *(const short8*)(zld + nidx * 40 + quad * 8);
  short8 az1 = *(const short8*)(zld + (16 + nidx) * 40 + quad * 8);
#pragma unroll
  for (int mat = 0; mat < NY; ++mat) {
    f32x4 ya[2][2];
#pragma unroll
    for (int mt = 0; mt < 2; ++mt)
#pragma unroll
      for (int nt = 0; nt < 2; ++nt) ya[mt][nt] = {0.f, 0.f, 0.f, 0.f};
#pragma unroll
    for (int nt = 0; nt < 2; ++nt) {
      short8 b = *(const short8*)(frag + (size_t)(fy + mat * 2 + nt) * 512 + lane * 8);
      ya[0][nt] = MFMA16(az0, b, ya[0][nt]);
      ya[1][nt] = MFMA16(az1, b, ya[1][nt]);
    }
#pragma unroll
    for (int mt = 0; mt < 2; ++mt)
#pragma unroll
      for (int nt = 0; nt < 2; ++nt)
#pragma unroll
        for (int r2 = 0; r2 < 4; ++r2)
          hld[(mt * 16 + quad * 4 + r2) * 40 + nt * 16 + nidx] = f2bf(ya[mt][nt][r2]);
    u16* yo = mat ? y2bf : y1bf;
    int rl = lane >> 1, hf = lane & 1;
    int grow = rows0 + rl;
    if (grow < N) {
      short8 v0 = *(const short8*)(hld + rl * 40 + hf * 16);
      short8 v1 = *(const short8*)(hld + rl * 40 + hf * 16 + 8);
      *(short8*)(yo + (size_t)grow * 32 + hf * 16) = v0;
      *(short8*)(yo + (size_t)grow * 32 + hf * 16 + 8) = v1;
    }
  }

  for (int chunk = 0; chunk < 4; ++chunk) {
    f32x4 fa[2][4];
#pragma unroll
    for (int mt = 0; mt < 2; ++mt)
#pragma unroll
      for (int nt = 0; nt < 4; ++nt) fa[mt][nt] = {0.f, 0.f, 0.f, 0.f};
#pragma unroll
    for (int nt = 0; nt < 4; ++nt) {
      short8 b = *(const short8*)(frag + (size_t)(fh + chunk * 4 + nt) * 512 + lane * 8);
      fa[0][nt] = MFMA16(az0, b, fa[0][nt]);
      fa[1][nt] = MFMA16(az1, b, fa[1][nt]);
    }
#pragma unroll
    for (int mt = 0; mt < 2; ++mt)
#pragma unroll
      for (int nt = 0; nt < 4; ++nt) {
        int col = chunk * 64 + nt * 16 + nidx;
        float hb = headb[col];
#pragma unroll
        for (int r2 = 0; r2 < 4; ++r2) {
          int grow = rows0 + mt * 16 + quad * 4 + r2;
          if (grow < N) flout[(size_t)grow * 256 + col] = fa[mt][nt][r2] + hb;
        }
      }
  }
}

__global__ void __launch_bounds__(256) k_node(
    const u16* __restrict__ x0A, const u16* __restrict__ mba, const u16* __restrict__ maa,
    const u16* __restrict__ x0B, const u16* __restrict__ mab,
    const u16* __restrict__ frag, const float* __restrict__ bhA,
    const float* __restrict__ bl_ab,
    const float* __restrict__ projbA, const float* __restrict__ headbA,
    const float* __restrict__ projbB, const float* __restrict__ headbB,
    float* __restrict__ zA, float* __restrict__ flA, u16* __restrict__ zAbf,
    u16* __restrict__ ybabf, u16* __restrict__ yaabf,
    float* __restrict__ zB, float* __restrict__ flB, u16* __restrict__ zBbf,
    u16* __restrict__ yabbf) {
  __shared__ u16 lds[4][3584];  // per-wave: h 32x72, z 32x40
  int t = threadIdx.x, lane = t & 63, w = t >> 6;
  u16* hld = &lds[w][0];
  u16* zld = &lds[w][2304];
  int blk = blockIdx.x;
  if (blk < 391) {
    node_chain<6, 2>(x0A, mba, maa, frag, 0, 24, 44, 28, bhA, projbA, headbA,
                     zA, flA, zAbf, ybabf, yaabf, blk * 128 + w * 32, NA, hld, zld, lane);
  } else {
    node_chain<4, 1>(x0B, mab, mab, frag, 48, 64, 84, 68, bl_ab, projbB, headbB,
                     zB, flB, zBbf, yabbf, yabbf, (blk - 391) * 128 + w * 32, NB, hld,
                     zld, lane);
  }
}

// ---------------- K5: bilinear edge scores, ONE RELATION PER LAUNCH --------------
__global__ void k_bil_rel(const int* __restrict__ ei,
                          const u16* __restrict__ zs, const u16* __restrict__ yd,
                          const float* __restrict__ bb, float* __restrict__ so) {
  int le = blockIdx.x * 256 + threadIdx.x;  // grid exactly NE/256
  int si = ei[le], di = ei[NE + le];
  const uint4* zp = (const uint4*)(zs + (size_t)si * 32);
  const uint4* yp = (const uint4*)(yd + (size_t)di * 32);
  float acc = 0.f;
#pragma unroll
  for (int i = 0; i < 4; ++i) {
    uint4 a = zp[i], c = yp[i];
    acc += bfl(a.x) * bfl(c.x) + bfh(a.x) * bfh(c.x);
    acc += bfl(a.y) * bfl(c.y) + bfh(a.y) * bfh(c.y);
    acc += bfl(a.z) * bfl(c.z) + bfh(a.z) * bfh(c.z);
    acc += bfl(a.w) * bfl(c.w) + bfh(a.w) * bfh(c.w);
  }
  so[le] = acc + bb[0];
}

extern "C" void kernel_launch(void* const* d_in, const int* in_sizes, int n_in,
                              void* d_out, int out_size, void* d_ws, size_t ws_size,
                              hipStream_t stream) {
  const int* xA = (const int*)d_in[0];
  const int* xB = (const int*)d_in[1];
  const int* ei_ab = (const int*)d_in[2];
  const int* ei_ba = (const int*)d_in[3];
  const int* ei_aa = (const int*)d_in[4];
  const float* embA = (const float*)d_in[5];
  const float* embB = (const float*)d_in[6];
  const float* preWA = (const float*)d_in[7];
  const float* prebA = (const float*)d_in[8];
  const float* preWB = (const float*)d_in[9];
  const float* prebB = (const float*)d_in[10];
  const float* Wl_ab = (const float*)d_in[11];
  const float* bl_ab = (const float*)d_in[12];
  const float* Wr_ab = (const float*)d_in[13];
  const float* Wl_ba = (const float*)d_in[14];
  const float* bl_ba = (const float*)d_in[15];
  const float* Wr_ba = (const float*)d_in[16];
  const float* Wl_aa = (const float*)d_in[17];
  const float* bl_aa = (const float*)d_in[18];
  const float* Wr_aa = (const float*)d_in[19];
  const float* projWA = (const float*)d_in[20];
  const float* projbA = (const float*)d_in[21];
  const float* projWB = (const float*)d_in[22];
  const float* projbB = (const float*)d_in[23];
  const float* headWA = (const float*)d_in[24];
  const float* headbA = (const float*)d_in[25];
  const float* headWB = (const float*)d_in[26];
  const float* headbB = (const float*)d_in[27];
  const float* bilW_ab = (const float*)d_in[28];
  const float* bilb_ab = (const float*)d_in[29];
  const float* bilW_ba = (const float*)d_in[30];
  const float* bilb_ba = (const float*)d_in[31];
  const float* bilW_aa = (const float*)d_in[32];
  const float* bilb_aa = (const float*)d_in[33];

  float* out = (float*)d_out;
  float* zA = out;                      // 50000*32
  float* zB = out + 1600000;            // 50000*32
  float* flA = out + 3200000;           // 50000*256
  float* flB = out + 16000000;          // 50000*256
  float* s_ab = out + 28800000;
  float* s_ba = out + 29600000;
  float* s_aa = out + 30400000;

  // workspace (byte offsets, all 16B-aligned)
  char* ws = (char*)d_ws;
  float* T = (float*)(ws + 0);            // 131072 B
  u16* x0Abf = (u16*)(ws + 131072);       // 6.4e6 B
  u16* x0Bbf = (u16*)(ws + 6531072);
  u16* mabbf = (u16*)(ws + 12931072);
  u16* mbabf = (u16*)(ws + 19331072);
  u16* maabf = (u16*)(ws + 25731072);
  u16* zAbf = (u16*)(ws + 32131072);      // 3.2e6 B
  u16* zBbf = (u16*)(ws + 35331072);
  u16* yabbf = (u16*)(ws + 38531072);
  u16* ybabf = (u16*)(ws + 41731072);
  u16* yaabf = (u16*)(ws + 44931072);
  int* cur = (int*)(ws + 48131072);       // 3*NBKT ints (dense)
  u16* frag = (u16*)(ws + 48731072);      // 88064 B
  float* bhA = (float*)(ws + 48819136);   // 256 B

  // coarse-bin buckets alias fl_A's d_out region (dead until k_node runs):
  // 3 * 782 * 1536 * 4B = 14.4 MB << 51.2 MB available
  u32* buckets = (u32*)flA;

  hipMemsetAsync(cur, 0, 3 * NBKT * sizeof(int), stream);
  k_pre<<<150, 256, 0, stream>>>(
      embA, embB, preWA, preWB, T,
      Wr_ba, Wr_aa, Wl_ba, Wl_aa, Wl_ab, Wr_ab, bl_ba, bl_aa,
      projWA, projWB, headWA, headWB, bilW_ba, bilW_aa, bilW_ab,
      frag, bhA);
  k_msx0<<<MSB + 2 * 782, 256, 0, stream>>>(
      xA, xB, T, prebA, prebB, x0Abf, x0Bbf,
      ei_ab, ei_ba, ei_aa, cur, buckets);
  // order ab -> aa -> ba keeps x0A hot in L2 across the first two launches
  k_meansort_rel<<<NBKT, 256, 0, stream>>>(buckets, cur, x0Abf, mabbf);
  k_meansort_rel<<<NBKT, 256, 0, stream>>>(buckets + (size_t)2 * NBKT * CAPB,
                                           cur + 2 * NBKT, x0Abf, maabf);
  k_meansort_rel<<<NBKT, 256, 0, stream>>>(buckets + (size_t)NBKT * CAPB,
                                           cur + NBKT, x0Bbf, mbabf);
  k_node<<<782, 256, 0, stream>>>(x0Abf, mbabf, maabf, x0Bbf, mabbf, frag, bhA,
                                  bl_ab, projbA, headbA, projbB, headbB,
                                  zA, flA, zAbf, ybabf, yaabf, zB, flB, zBbf, yabbf);
  k_bil_rel<<<NE / 256, 256, 0, stream>>>(ei_ab, zAbf, yabbf, bilb_ab, s_ab);
  k_bil_rel<<<NE / 256, 256, 0, stream>>>(ei_ba, zBbf, ybabf, bilb_ba, s_ba);
  k_bil_rel<<<NE / 256, 256, 0, stream>>>(ei_aa, zAbf, yaabf, bilb_aa, s_aa);
}

// Round 14
// 357.174 us; speedup vs baseline: 1.1351x; 1.1351x over previous
//
#include <hip/hip_runtime.h>

typedef unsigned short u16;
typedef unsigned int u32;
typedef __attribute__((ext_vector_type(8))) short short8;  // 8 bf16 (4 VGPRs)
typedef __attribute__((ext_vector_type(4))) float f32x4;

constexpr int NA = 50000, NB = 50000;
constexpr int EMB = 16, HID = 64;
constexpr int NE = 800000;
constexpr int NBKT = 782;   // buckets per relation, 64 dsts each (782*64=50048)
constexpr int CAPB = 1536;  // bucket capacity: mean 1024, sd 32 -> +16 sd
constexpr int EPB = 4096;   // edges per multisplit block (196 blocks/relation)
constexpr int BPR = (NE + EPB - 1) / EPB;  // 196
constexpr int MSB = 3 * BPR;               // 588 multisplit blocks (2.3/CU tail)

#define MFMA16(a, b, c) __builtin_amdgcn_mfma_f32_16x16x32_bf16(a, b, c, 0, 0, 0)

__device__ inline u16 f2bf(float f) {  // RNE f32->bf16
  u32 b = __float_as_uint(f);
  return (u16)((b + 0x7FFFu + ((b >> 16) & 1u)) >> 16);
}
__device__ inline float bfl(u32 u) { return __uint_as_float(u << 16); }
__device__ inline float bfh(u32 u) { return __uint_as_float(u & 0xFFFF0000u); }
__device__ inline float bfs(u16 u) { return __uint_as_float((u32)u << 16); }

// ---------------- K0: tables (ROW-major T2[fdbin][col]) + weight-prep ------------
__global__ void __launch_bounds__(256) k_pre(
    const float* __restrict__ embA, const float* __restrict__ embB,
    const float* __restrict__ preWA, const float* __restrict__ preWB,
    float* __restrict__ T,
    const float* __restrict__ Wr_ba, const float* __restrict__ Wr_aa,
    const float* __restrict__ Wl_ba, const float* __restrict__ Wl_aa,
    const float* __restrict__ Wl_ab, const float* __restrict__ Wr_ab,
    const float* __restrict__ bl_ba, const float* __restrict__ bl_aa,
    const float* __restrict__ projWA, const float* __restrict__ projWB,
    const float* __restrict__ headWA, const float* __restrict__ headWB,
    const float* __restrict__ bilW_ba, const float* __restrict__ bilW_aa,
    const float* __restrict__ bilW_ab,
    u16* __restrict__ frag, float* __restrict__ bhA) {
  int blk = blockIdx.x;
  int t = threadIdx.x;

  if (blk < 128) {  // ---- tables ----
    int id = blk * 256 + t;  // 0..32767
    int type = id >> 14;
    int rem = id & 16383;
    int fdbin = rem >> 6;  // 0..255
    int col = rem & 63;    // 0..63 (lane-fast -> coalesced)
    int fd = fdbin >> 5;
    const float* emb = type ? embB : embA;
    const float* W = type ? preWB : preWA;
    const float* e = emb + fdbin * EMB;
    const float* w = W + (fd * EMB) * HID + col;
    float s = 0.f;
#pragma unroll
    for (int j = 0; j < EMB; ++j) s += e[j] * w[j * HID];
    T[id] = s;
    return;
  }

  // ---- prep ----
  int tid = (blk - 128) * 256 + t;  // 0..5631
  if (tid >= 86 * 64) {
    int i = tid - 86 * 64;
    if (i < 64) bhA[i] = 0.5f * (bl_ba[i] + bl_aa[i]);
    return;
  }
  int f = tid >> 6, lane = tid & 63;
  int nidx = lane & 15, quad = lane >> 4;
  u16* dst = frag + (size_t)f * 512 + lane * 8;
#pragma unroll
  for (int j = 0; j < 8; ++j) {
    int kq = quad * 8 + j;
    float v;
    if (f < 24) {
      int s = f >> 2, nt = f & 3, k = s * 32 + kq, c = nt * 16 + nidx;
      v = (k < 64) ? 0.5f * (Wr_ba[k * 64 + c] + Wr_aa[k * 64 + c])
          : (k < 128) ? 0.5f * Wl_ba[(k - 64) * 64 + c]
                      : 0.5f * Wl_aa[(k - 128) * 64 + c];
    } else if (f < 28) {
      int g = f - 24, k = (g >> 1) * 32 + kq, c = (g & 1) * 16 + nidx;
      v = projWA[k * 32 + c];
    } else if (f < 44) {
      int c = (f - 28) * 16 + nidx;
      v = headWA[kq * 256 + c];
    } else if (f < 46) {
      int i2 = (f - 44) * 16 + nidx;
      v = bilW_ba[i2 * 32 + kq];
    } else if (f < 48) {
      int i2 = (f - 46) * 16 + nidx;
      v = bilW_aa[i2 * 32 + kq];
    } else if (f < 64) {
      int g = f - 48, s = g >> 2, nt = g & 3, k = s * 32 + kq, c = nt * 16 + nidx;
      v = (k < 64) ? Wr_ab[k * 64 + c] : Wl_ab[(k - 64) * 64 + c];
    } else if (f < 68) {
      int g = f - 64, k = (g >> 1) * 32 + kq, c = (g & 1) * 16 + nidx;
      v = projWB[k * 32 + c];
    } else if (f < 84) {
      int c = (f - 68) * 16 + nidx;
      v = headWB[kq * 256 + c];
    } else {
      int i2 = (f - 84) * 16 + nidx;
      v = bilW_ab[i2 * 32 + kq];
    }
    dst[j] = f2bf(v);
  }
}

// ---------------- K1: fused multisplit + x0-direct (one launch) ------------------
__global__ void __launch_bounds__(256) k_msx0(
    const int* __restrict__ xA, const int* __restrict__ xB,
    const float* __restrict__ T,
    const float* __restrict__ biasA, const float* __restrict__ biasB,
    u16* __restrict__ x0A, u16* __restrict__ x0B,
    const int* __restrict__ ei_ab, const int* __restrict__ ei_ba,
    const int* __restrict__ ei_aa, int* __restrict__ gcur,
    u32* __restrict__ buckets) {
  __shared__ u32 ebuf2[EPB];   // 16KB sorted staging
  __shared__ int hist[NBKT];   // counts -> ranked-write cursor
  __shared__ int loff[NBKT];   // local exclusive prefix
  __shared__ int delta[NBKT];  // global_off - local_off per bucket
  __shared__ int scanw[256];
  int blk = blockIdx.x;
  int t = threadIdx.x;

  if (blk < MSB) {  // ---- multisplit ----
    int rel = blk / BPR;
    int lb = blk - rel * BPR;
    const int* ei = rel == 0 ? ei_ab : (rel == 1 ? ei_ba : ei_aa);
    int e0 = lb * EPB;
    int n = min(EPB, NE - e0);
    for (int i = t; i < NBKT; i += 256) hist[i] = 0;
    __syncthreads();
    // pass 1: histogram
    for (int i = t; i < n; i += 256) {
      int dstn = ei[NE + e0 + i];
      atomicAdd(&hist[dstn >> 6], 1);
    }
    __syncthreads();
    // exclusive prefix sum hist -> loff (4 entries/thread + scan over 256)
    int base4 = t * 4;
    int s = 0;
#pragma unroll
    for (int k = 0; k < 4; ++k) {
      int idx = base4 + k;
      if (idx < NBKT) s += hist[idx];
    }
    scanw[t] = s;
    __syncthreads();
    for (int off = 1; off < 256; off <<= 1) {
      int v = (t >= off) ? scanw[t - off] : 0;
      __syncthreads();
      scanw[t] += v;
      __syncthreads();
    }
    int run = (t == 0) ? 0 : scanw[t - 1];
#pragma unroll
    for (int k = 0; k < 4; ++k) {
      int idx = base4 + k;
      if (idx < NBKT) {
        loff[idx] = run;
        run += hist[idx];
      }
    }
    __syncthreads();
    // reserve global runs; hist becomes the running ranked-write cursor
    for (int i = t; i < NBKT; i += 256) {
      int c = hist[i];
      if (c > 0) {
        int g = atomicAdd(&gcur[rel * NBKT + i], c);
        delta[i] = g - loff[i];
      }
      hist[i] = loff[i];
    }
    __syncthreads();
    // pass 2a: ranked scatter into LDS, bucket id tagged in bits 22..31
    for (int i = t; i < n; i += 256) {
      int src = ei[e0 + i];
      int dstn = ei[NE + e0 + i];
      int b = dstn >> 6;
      int p = atomicAdd(&hist[b], 1);
      ebuf2[p] = ((u32)b << 22) | ((u32)src << 6) | (u32)(dstn & 63);
    }
    __syncthreads();
    // pass 2b: coalesced copy (consecutive j, same bucket -> consecutive gmem)
    for (int j = t; j < n; j += 256) {
      u32 v = ebuf2[j];
      int b = v >> 22;
      int gpos = delta[b] + j;  // = global_off + local_rank within bucket b
      if (gpos < CAPB)
        buckets[(size_t)(rel * NBKT + b) * CAPB + gpos] = v & 0x3FFFFFu;
    }
    return;
  }

  // ---- x0 direct-gather ----
  int xblk = blk - MSB;  // 0..1563
  int type = xblk >= 782;
  int lb = type ? xblk - 782 : xblk;
  const int* x = type ? xB : xA;
  const float4* Tv = (const float4*)(T + (type ? 16384 : 0));
  const float* bias = type ? biasB : biasA;
  u16* x0 = type ? x0B : x0A;
  const int N = NA;  // NA == NB

  int r = t >> 2, q = t & 3;
  int row = lb * 64 + r;
  bool valid = row < N;
  int arow = valid ? row : (N - 1);
  const int4* xp = (const int4*)(x + arow * 8);
  int4 xa = xp[0], xb = xp[1];
  int bins[8] = {xa.x, xa.y, xa.z, xa.w, xb.x, xb.y, xb.z, xb.w};
  int c0 = q * 16;
  float acc[16];
#pragma unroll
  for (int j = 0; j < 16; ++j) acc[j] = bias[c0 + j];
#pragma unroll
  for (int fd = 0; fd < 8; ++fd) {
    int base = (fd * 32 + bins[fd]) * 16 + q * 4;  // float4 index into T2 row
    float4 v0 = Tv[base], v1 = Tv[base + 1], v2 = Tv[base + 2], v3 = Tv[base + 3];
    acc[0] += v0.x;  acc[1] += v0.y;  acc[2] += v0.z;  acc[3] += v0.w;
    acc[4] += v1.x;  acc[5] += v1.y;  acc[6] += v1.z;  acc[7] += v1.w;
    acc[8] += v2.x;  acc[9] += v2.y;  acc[10] += v2.z; acc[11] += v2.w;
    acc[12] += v3.x; acc[13] += v3.y; acc[14] += v3.z; acc[15] += v3.w;
  }
  if (valid) {
    u32 p[8];
#pragma unroll
    for (int j = 0; j < 8; ++j) {
      u16 lo = f2bf(fmaxf(acc[2 * j], 0.f));
      u16 hi = f2bf(fmaxf(acc[2 * j + 1], 0.f));
      p[j] = (u32)lo | ((u32)hi << 16);
    }
    u32* o = (u32*)(x0 + (size_t)row * 64 + c0);
    *(uint4*)o = *(uint4*)&p[0];
    *((uint4*)o + 1) = *(uint4*)&p[4];
  }
}

// ---------------- K3: per-bucket LDS counting-sort + gather-mean ----------------
// Single 2346-block launch (R12 config). R13's 3-launch half-dim variant
// regressed +48us: per-launch occupancy fell to ~3 blocks/CU (vs 8 resident)
// and the 2-pass gather doubled instructions/chain while touching the SAME
// 2 cache lines per edge-row. Reverted.
__global__ void __launch_bounds__(256) k_meansort_all(
    const u32* __restrict__ buckets, const int* __restrict__ cur,
    const u16* __restrict__ x0A, const u16* __restrict__ x0B,
    u16* __restrict__ mab, u16* __restrict__ mba, u16* __restrict__ maa) {
  __shared__ u32 ebuf[CAPB];
  __shared__ u16 csr[CAPB];
  __shared__ int dcnt[64], doff[64], wcur[64];
  int blk = blockIdx.x;  // 0..3*NBKT-1
  int rel = blk / NBKT;
  int lb = blk - rel * NBKT;
  int t = threadIdx.x;
  const u16* x0 = (rel == 1) ? x0B : x0A;
  u16* out = rel == 0 ? mab : (rel == 1 ? mba : maa);
  int n = min(cur[blk], CAPB);
  const u32* bk = buckets + (size_t)blk * CAPB;
  if (t < 64) dcnt[t] = 0;
  __syncthreads();
  for (int i = t; i < n; i += 256) {
    u32 v = bk[i];
    ebuf[i] = v;
    atomicAdd(&dcnt[v & 63], 1);
  }
  __syncthreads();
  if (t == 0) {
    int s = 0;
#pragma unroll
    for (int d = 0; d < 64; ++d) {
      doff[d] = s;
      wcur[d] = s;
      s += dcnt[d];
    }
  }
  __syncthreads();
  for (int i = t; i < n; i += 256) {
    u32 v = ebuf[i];
    int p = atomicAdd(&wcur[v & 63], 1);
    csr[p] = (u16)(v >> 6);
  }
  __syncthreads();
  int lane = t & 63, w = t >> 6;
  int g = lane >> 4;           // dst sub-group 0..3 within wave
  int dim4 = (lane & 15) * 4;  // this lane's exclusive 4 dims
  int base = lb * 64;
  for (int c = 0; c < 4; ++c) {
    int dloc = w * 16 + c * 4 + g;
    int dstn = base + dloc;
    if (dstn < 50000) {
      int off = doff[dloc], deg = dcnt[dloc];
      float a0 = 0.f, a1 = 0.f, a2 = 0.f, a3 = 0.f;
      int i = 0;
      for (; i + 8 <= deg; i += 8) {
        uint2 v0 = *(const uint2*)(x0 + (size_t)csr[off + i] * 64 + dim4);
        uint2 v1 = *(const uint2*)(x0 + (size_t)csr[off + i + 1] * 64 + dim4);
        uint2 v2 = *(const uint2*)(x0 + (size_t)csr[off + i + 2] * 64 + dim4);
        uint2 v3 = *(const uint2*)(x0 + (size_t)csr[off + i + 3] * 64 + dim4);
        uint2 v4 = *(const uint2*)(x0 + (size_t)csr[off + i + 4] * 64 + dim4);
        uint2 v5 = *(const uint2*)(x0 + (size_t)csr[off + i + 5] * 64 + dim4);
        uint2 v6 = *(const uint2*)(x0 + (size_t)csr[off + i + 6] * 64 + dim4);
        uint2 v7 = *(const uint2*)(x0 + (size_t)csr[off + i + 7] * 64 + dim4);
        a0 += bfl(v0.x) + bfl(v1.x) + bfl(v2.x) + bfl(v3.x) +
              bfl(v4.x) + bfl(v5.x) + bfl(v6.x) + bfl(v7.x);
        a1 += bfh(v0.x) + bfh(v1.x) + bfh(v2.x) + bfh(v3.x) +
              bfh(v4.x) + bfh(v5.x) + bfh(v6.x) + bfh(v7.x);
        a2 += bfl(v0.y) + bfl(v1.y) + bfl(v2.y) + bfl(v3.y) +
              bfl(v4.y) + bfl(v5.y) + bfl(v6.y) + bfl(v7.y);
        a3 += bfh(v0.y) + bfh(v1.y) + bfh(v2.y) + bfh(v3.y) +
              bfh(v4.y) + bfh(v5.y) + bfh(v6.y) + bfh(v7.y);
      }
      for (; i + 4 <= deg; i += 4) {
        uint2 v0 = *(const uint2*)(x0 + (size_t)csr[off + i] * 64 + dim4);
        uint2 v1 = *(const uint2*)(x0 + (size_t)csr[off + i + 1] * 64 + dim4);
        uint2 v2 = *(const uint2*)(x0 + (size_t)csr[off + i + 2] * 64 + dim4);
        uint2 v3 = *(const uint2*)(x0 + (size_t)csr[off + i + 3] * 64 + dim4);
        a0 += bfl(v0.x) + bfl(v1.x) + bfl(v2.x) + bfl(v3.x);
        a1 += bfh(v0.x) + bfh(v1.x) + bfh(v2.x) + bfh(v3.x);
        a2 += bfl(v0.y) + bfl(v1.y) + bfl(v2.y) + bfl(v3.y);
        a3 += bfh(v0.y) + bfh(v1.y) + bfh(v2.y) + bfh(v3.y);
      }
      for (; i < deg; ++i) {
        uint2 v0 = *(const uint2*)(x0 + (size_t)csr[off + i] * 64 + dim4);
        a0 += bfl(v0.x);
        a1 += bfh(v0.x);
        a2 += bfl(v0.y);
        a3 += bfh(v0.y);
      }
      float inv = deg > 0 ? 1.f / (float)deg : 0.f;
      uint2 o;
      o.x = (u32)f2bf(a0 * inv) | ((u32)f2bf(a1 * inv) << 16);
      o.y = (u32)f2bf(a2 * inv) | ((u32)f2bf(a3 * inv) << 16);
      *(uint2*)(out + (size_t)dstn * 64 + dim4) = o;
    }
  }
}

// ---------------- K4: fused MFMA node chain (A and B in one grid) ----------------
template <int NS, int NY>
__device__ __forceinline__ void node_chain(
    const u16* __restrict__ x0, const u16* __restrict__ m1, const u16* __restrict__ m2,
    const u16* __restrict__ frag, int f1, int f2, int fy, int fh,
    const float* __restrict__ hbias, const float* __restrict__ projb,
    const float* __restrict__ headb,
    float* __restrict__ zout, float* __restrict__ flout,
    u16* __restrict__ zbf, u16* __restrict__ y1bf, u16* __restrict__ y2bf,
    int rows0, int N, u16* hld, u16* zld, int lane) {
  int nidx = lane & 15, quad = lane >> 4;
  size_t r0 = (size_t)min(rows0 + nidx, N - 1);
  size_t r1 = (size_t)min(rows0 + 16 + nidx, N - 1);

  f32x4 acc[2][4];
#pragma unroll
  for (int mt = 0; mt < 2; ++mt)
#pragma unroll
    for (int nt = 0; nt < 4; ++nt) acc[mt][nt] = {0.f, 0.f, 0.f, 0.f};
  const u16* mats[3] = {x0, m1, m2};
#pragma unroll
  for (int s = 0; s < NS; ++s) {
    const u16* src = mats[s >> 1];
    int koff = (s & 1) * 32 + quad * 8;
    short8 a0 = *(const short8*)(src + r0 * 64 + koff);
    short8 a1 = *(const short8*)(src + r1 * 64 + koff);
#pragma unroll
    for (int nt = 0; nt < 4; ++nt) {
      short8 b = *(const short8*)(frag + (size_t)(f1 + s * 4 + nt) * 512 + lane * 8);
      acc[0][nt] = MFMA16(a0, b, acc[0][nt]);
      acc[1][nt] = MFMA16(a1, b, acc[1][nt]);
    }
  }
#pragma unroll
  for (int mt = 0; mt < 2; ++mt)
#pragma unroll
    for (int nt = 0; nt < 4; ++nt) {
      int col = nt * 16 + nidx;
      float bb = hbias[col];
#pragma unroll
      for (int r2 = 0; r2 < 4; ++r2)
        hld[(mt * 16 + quad * 4 + r2) * 72 + col] = f2bf(acc[mt][nt][r2] + bb);
    }

  f32x4 zacc[2][2];
#pragma unroll
  for (int mt = 0; mt < 2; ++mt)
#pragma unroll
    for (int nt = 0; nt < 2; ++nt) zacc[mt][nt] = {0.f, 0.f, 0.f, 0.f};
#pragma unroll
  for (int s = 0; s < 2; ++s) {
    short8 a0 = *(const short8*)(hld + nidx * 72 + s * 32 + quad * 8);
    short8 a1 = *(const short8*)(hld + (16 + nidx) * 72 + s * 32 + quad * 8);
#pragma unroll
    for (int nt = 0; nt < 2; ++nt) {
      short8 b = *(const short8*)(frag + (size_t)(f2 + s * 2 + nt) * 512 + lane * 8);
      zacc[0][nt] = MFMA16(a0, b, zacc[0][nt]);
      zacc[1][nt] = MFMA16(a1, b, zacc[1][nt]);
    }
  }
#pragma unroll
  for (int mt = 0; mt < 2; ++mt)
#pragma unroll
    for (int nt = 0; nt < 2; ++nt) {
      int col = nt * 16 + nidx;
      float pb = projb[col];
#pragma unroll
      for (int r2 = 0; r2 < 4; ++r2) {
        int rl = mt * 16 + quad * 4 + r2;
        float zv = fmaxf(zacc[mt][nt][r2] + pb, 0.f);
        zld[rl * 40 + col] = f2bf(zv);
        int grow = rows0 + rl;
        if (grow < N) zout[(size_t)grow * 32 + col] = zv;
      }
    }
  {  // coalesced bf16 z store (2 lanes per row)
    int rl = lane >> 1, hf = lane & 1;
    int grow = rows0 + rl;
    if (grow < N) {
      short8 v0 = *(const short8*)(zld + rl * 40 + hf * 16);
      short8 v1 = *(const short8*)(zld + rl * 40 + hf * 16 + 8);
      *(short8*)(zbf + (size_t)grow * 32 + hf * 16) = v0;
      *(short8*)(zbf + (size_t)grow * 32 + hf * 16 + 8) = v1;
    }
  }

  short8 az0 = *(const short8*)(zld + nidx * 40 + quad * 8);
  short8 az1 = *(const short8*)(zld + (16 + nidx) * 40 + quad * 8);
#pragma unroll
  for (int mat = 0; mat < NY; ++mat) {
    f32x4 ya[2][2];
#pragma unroll
    for (int mt = 0; mt < 2; ++mt)
#pragma unroll
      for (int nt = 0; nt < 2; ++nt) ya[mt][nt] = {0.f, 0.f, 0.f, 0.f};
#pragma unroll
    for (int nt = 0; nt < 2; ++nt) {
      short8 b = *(const short8*)(frag + (size_t)(fy + mat * 2 + nt) * 512 + lane * 8);
      ya[0][nt] = MFMA16(az0, b, ya[0][nt]);
      ya[1][nt] = MFMA16(az1, b, ya[1][nt]);
    }
#pragma unroll
    for (int mt = 0; mt < 2; ++mt)
#pragma unroll
      for (int nt = 0; nt < 2; ++nt)
#pragma unroll
        for (int r2 = 0; r2 < 4; ++r2)
          hld[(mt * 16 + quad * 4 + r2) * 40 + nt * 16 + nidx] = f2bf(ya[mt][nt][r2]);
    u16* yo = mat ? y2bf : y1bf;
    int rl = lane >> 1, hf = lane & 1;
    int grow = rows0 + rl;
    if (grow < N) {
      short8 v0 = *(const short8*)(hld + rl * 40 + hf * 16);
      short8 v1 = *(const short8*)(hld + rl * 40 + hf * 16 + 8);
      *(short8*)(yo + (size_t)grow * 32 + hf * 16) = v0;
      *(short8*)(yo + (size_t)grow * 32 + hf * 16 + 8) = v1;
    }
  }

  for (int chunk = 0; chunk < 4; ++chunk) {
    f32x4 fa[2][4];
#pragma unroll
    for (int mt = 0; mt < 2; ++mt)
#pragma unroll
      for (int nt = 0; nt < 4; ++nt) fa[mt][nt] = {0.f, 0.f, 0.f, 0.f};
#pragma unroll
    for (int nt = 0; nt < 4; ++nt) {
      short8 b = *(const short8*)(frag + (size_t)(fh + chunk * 4 + nt) * 512 + lane * 8);
      fa[0][nt] = MFMA16(az0, b, fa[0][nt]);
      fa[1][nt] = MFMA16(az1, b, fa[1][nt]);
    }
#pragma unroll
    for (int mt = 0; mt < 2; ++mt)
#pragma unroll
      for (int nt = 0; nt < 4; ++nt) {
        int col = chunk * 64 + nt * 16 + nidx;
        float hb = headb[col];
#pragma unroll
        for (int r2 = 0; r2 < 4; ++r2) {
          int grow = rows0 + mt * 16 + quad * 4 + r2;
          if (grow < N) flout[(size_t)grow * 256 + col] = fa[mt][nt][r2] + hb;
        }
      }
  }
}

__global__ void __launch_bounds__(256) k_node(
    const u16* __restrict__ x0A, const u16* __restrict__ mba, const u16* __restrict__ maa,
    const u16* __restrict__ x0B, const u16* __restrict__ mab,
    const u16* __restrict__ frag, const float* __restrict__ bhA,
    const float* __restrict__ bl_ab,
    const float* __restrict__ projbA, const float* __restrict__ headbA,
    const float* __restrict__ projbB, const float* __restrict__ headbB,
    float* __restrict__ zA, float* __restrict__ flA, u16* __restrict__ zAbf,
    u16* __restrict__ ybabf, u16* __restrict__ yaabf,
    float* __restrict__ zB, float* __restrict__ flB, u16* __restrict__ zBbf,
    u16* __restrict__ yabbf) {
  __shared__ u16 lds[4][3584];  // per-wave: h 32x72, z 32x40
  int t = threadIdx.x, lane = t & 63, w = t >> 6;
  u16* hld = &lds[w][0];
  u16* zld = &lds[w][2304];
  int blk = blockIdx.x;
  if (blk < 391) {
    node_chain<6, 2>(x0A, mba, maa, frag, 0, 24, 44, 28, bhA, projbA, headbA,
                     zA, flA, zAbf, ybabf, yaabf, blk * 128 + w * 32, NA, hld, zld, lane);
  } else {
    node_chain<4, 1>(x0B, mab, mab, frag, 48, 64, 84, 68, bl_ab, projbB, headbB,
                     zB, flB, zBbf, yabbf, yabbf, (blk - 391) * 128 + w * 32, NB, hld,
                     zld, lane);
  }
}

// ---------------- K5: bilinear edge scores, ONE RELATION PER LAUNCH --------------
__global__ void k_bil_rel(const int* __restrict__ ei,
                          const u16* __restrict__ zs, const u16* __restrict__ yd,
                          const float* __restrict__ bb, float* __restrict__ so) {
  int le = blockIdx.x * 256 + threadIdx.x;  // grid exactly NE/256
  int si = ei[le], di = ei[NE + le];
  const uint4* zp = (const uint4*)(zs + (size_t)si * 32);
  const uint4* yp = (const uint4*)(yd + (size_t)di * 32);
  float acc = 0.f;
#pragma unroll
  for (int i = 0; i < 4; ++i) {
    uint4 a = zp[i], c = yp[i];
    acc += bfl(a.x) * bfl(c.x) + bfh(a.x) * bfh(c.x);
    acc += bfl(a.y) * bfl(c.y) + bfh(a.y) * bfh(c.y);
    acc += bfl(a.z) * bfl(c.z) + bfh(a.z) * bfh(c.z);
    acc += bfl(a.w) * bfl(c.w) + bfh(a.w) * bfh(c.w);
  }
  so[le] = acc + bb[0];
}

extern "C" void kernel_launch(void* const* d_in, const int* in_sizes, int n_in,
                              void* d_out, int out_size, void* d_ws, size_t ws_size,
                              hipStream_t stream) {
  const int* xA = (const int*)d_in[0];
  const int* xB = (const int*)d_in[1];
  const int* ei_ab = (const int*)d_in[2];
  const int* ei_ba = (const int*)d_in[3];
  const int* ei_aa = (const int*)d_in[4];
  const float* embA = (const float*)d_in[5];
  const float* embB = (const float*)d_in[6];
  const float* preWA = (const float*)d_in[7];
  const float* prebA = (const float*)d_in[8];
  const float* preWB = (const float*)d_in[9];
  const float* prebB = (const float*)d_in[10];
  const float* Wl_ab = (const float*)d_in[11];
  const float* bl_ab = (const float*)d_in[12];
  const float* Wr_ab = (const float*)d_in[13];
  const float* Wl_ba = (const float*)d_in[14];
  const float* bl_ba = (const float*)d_in[15];
  const float* Wr_ba = (const float*)d_in[16];
  const float* Wl_aa = (const float*)d_in[17];
  const float* bl_aa = (const float*)d_in[18];
  const float* Wr_aa = (const float*)d_in[19];
  const float* projWA = (const float*)d_in[20];
  const float* projbA = (const float*)d_in[21];
  const float* projWB = (const float*)d_in[22];
  const float* projbB = (const float*)d_in[23];
  const float* headWA = (const float*)d_in[24];
  const float* headbA = (const float*)d_in[25];
  const float* headWB = (const float*)d_in[26];
  const float* headbB = (const float*)d_in[27];
  const float* bilW_ab = (const float*)d_in[28];
  const float* bilb_ab = (const float*)d_in[29];
  const float* bilW_ba = (const float*)d_in[30];
  const float* bilb_ba = (const float*)d_in[31];
  const float* bilW_aa = (const float*)d_in[32];
  const float* bilb_aa = (const float*)d_in[33];

  float* out = (float*)d_out;
  float* zA = out;                      // 50000*32
  float* zB = out + 1600000;            // 50000*32
  float* flA = out + 3200000;           // 50000*256
  float* flB = out + 16000000;          // 50000*256
  float* s_ab = out + 28800000;
  float* s_ba = out + 29600000;
  float* s_aa = out + 30400000;

  // workspace (byte offsets, all 16B-aligned)
  char* ws = (char*)d_ws;
  float* T = (float*)(ws + 0);            // 131072 B
  u16* x0Abf = (u16*)(ws + 131072);       // 6.4e6 B
  u16* x0Bbf = (u16*)(ws + 6531072);
  u16* mabbf = (u16*)(ws + 12931072);
  u16* mbabf = (u16*)(ws + 19331072);
  u16* maabf = (u16*)(ws + 25731072);
  u16* zAbf = (u16*)(ws + 32131072);      // 3.2e6 B
  u16* zBbf = (u16*)(ws + 35331072);
  u16* yabbf = (u16*)(ws + 38531072);
  u16* ybabf = (u16*)(ws + 41731072);
  u16* yaabf = (u16*)(ws + 44931072);
  int* cur = (int*)(ws + 48131072);       // 3*NBKT ints (dense)
  u16* frag = (u16*)(ws + 48731072);      // 88064 B
  float* bhA = (float*)(ws + 48819136);   // 256 B

  // coarse-bin buckets alias fl_A's d_out region (dead until k_node runs):
  // 3 * 782 * 1536 * 4B = 14.4 MB << 51.2 MB available
  u32* buckets = (u32*)flA;

  hipMemsetAsync(cur, 0, 3 * NBKT * sizeof(int), stream);
  k_pre<<<150, 256, 0, stream>>>(
      embA, embB, preWA, preWB, T,
      Wr_ba, Wr_aa, Wl_ba, Wl_aa, Wl_ab, Wr_ab, bl_ba, bl_aa,
      projWA, projWB, headWA, headWB, bilW_ba, bilW_aa, bilW_ab,
      frag, bhA);
  k_msx0<<<MSB + 2 * 782, 256, 0, stream>>>(
      xA, xB, T, prebA, prebB, x0Abf, x0Bbf,
      ei_ab, ei_ba, ei_aa, cur, buckets);
  k_meansort_all<<<3 * NBKT, 256, 0, stream>>>(buckets, cur, x0Abf, x0Bbf,
                                               mabbf, mbabf, maabf);
  k_node<<<782, 256, 0, stream>>>(x0Abf, mbabf, maabf, x0Bbf, mabbf, frag, bhA,
                                  bl_ab, projbA, headbA, projbB, headbB,
                                  zA, flA, zAbf, ybabf, yaabf, zB, flB, zBbf, yabbf);
  k_bil_rel<<<NE / 256, 256, 0, stream>>>(ei_ab, zAbf, yabbf, bilb_ab, s_ab);
  k_bil_rel<<<NE / 256, 256, 0, stream>>>(ei_ba, zBbf, ybabf, bilb_ba, s_ba);
  k_bil_rel<<<NE / 256, 256, 0, stream>>>(ei_aa, zAbf, yaabf, bilb_aa, s_aa);
}

// Round 15
// 348.757 us; speedup vs baseline: 1.1625x; 1.0241x over previous
//
#include <hip/hip_runtime.h>

typedef unsigned short u16;
typedef unsigned int u32;
typedef __attribute__((ext_vector_type(8))) short short8;  // 8 bf16 (4 VGPRs)
typedef __attribute__((ext_vector_type(4))) float f32x4;

constexpr int NA = 50000, NB = 50000;
constexpr int EMB = 16, HID = 64;
constexpr int NE = 800000;
constexpr int NBKT = 782;   // buckets per relation, 64 dsts each (782*64=50048)
constexpr int CAPB = 1536;  // bucket capacity: mean 1024, sd 32 -> +16 sd
constexpr int EPB = 4096;   // edges per multisplit block (196 blocks/relation)
constexpr int BPR = (NE + EPB - 1) / EPB;  // 196
constexpr int MSB = 3 * BPR;               // 588 multisplit blocks (2.3/CU tail)

#define MFMA16(a, b, c) __builtin_amdgcn_mfma_f32_16x16x32_bf16(a, b, c, 0, 0, 0)

__device__ inline u16 f2bf(float f) {  // RNE f32->bf16
  u32 b = __float_as_uint(f);
  return (u16)((b + 0x7FFFu + ((b >> 16) & 1u)) >> 16);
}
__device__ inline float bfl(u32 u) { return __uint_as_float(u << 16); }
__device__ inline float bfh(u32 u) { return __uint_as_float(u & 0xFFFF0000u); }
__device__ inline float bfs(u16 u) { return __uint_as_float((u32)u << 16); }

// ---------------- K0: tables (ROW-major T2[fdbin][col]) + weight-prep + cur=0 ----
__global__ void __launch_bounds__(256) k_pre(
    const float* __restrict__ embA, const float* __restrict__ embB,
    const float* __restrict__ preWA, const float* __restrict__ preWB,
    float* __restrict__ T,
    const float* __restrict__ Wr_ba, const float* __restrict__ Wr_aa,
    const float* __restrict__ Wl_ba, const float* __restrict__ Wl_aa,
    const float* __restrict__ Wl_ab, const float* __restrict__ Wr_ab,
    const float* __restrict__ bl_ba, const float* __restrict__ bl_aa,
    const float* __restrict__ projWA, const float* __restrict__ projWB,
    const float* __restrict__ headWA, const float* __restrict__ headWB,
    const float* __restrict__ bilW_ba, const float* __restrict__ bilW_aa,
    const float* __restrict__ bilW_ab,
    u16* __restrict__ frag, float* __restrict__ bhA, int* __restrict__ gcur) {
  int blk = blockIdx.x;
  int t = threadIdx.x;

  if (blk < 128) {  // ---- tables ----
    int id = blk * 256 + t;  // 0..32767
    int type = id >> 14;
    int rem = id & 16383;
    int fdbin = rem >> 6;  // 0..255
    int col = rem & 63;    // 0..63 (lane-fast -> coalesced)
    int fd = fdbin >> 5;
    const float* emb = type ? embB : embA;
    const float* W = type ? preWB : preWA;
    const float* e = emb + fdbin * EMB;
    const float* w = W + (fd * EMB) * HID + col;
    float s = 0.f;
#pragma unroll
    for (int j = 0; j < EMB; ++j) s += e[j] * w[j * HID];
    T[id] = s;
    return;
  }

  if (blk == 150) {  // ---- zero bucket cursors (replaces memset dispatch) ----
    for (int i = t; i < 3 * NBKT; i += 256) gcur[i] = 0;
    return;
  }

  // ---- prep ----
  int tid = (blk - 128) * 256 + t;  // 0..5631
  if (tid >= 86 * 64) {
    int i = tid - 86 * 64;
    if (i < 64) bhA[i] = 0.5f * (bl_ba[i] + bl_aa[i]);
    return;
  }
  int f = tid >> 6, lane = tid & 63;
  int nidx = lane & 15, quad = lane >> 4;
  u16* dst = frag + (size_t)f * 512 + lane * 8;
#pragma unroll
  for (int j = 0; j < 8; ++j) {
    int kq = quad * 8 + j;
    float v;
    if (f < 24) {
      int s = f >> 2, nt = f & 3, k = s * 32 + kq, c = nt * 16 + nidx;
      v = (k < 64) ? 0.5f * (Wr_ba[k * 64 + c] + Wr_aa[k * 64 + c])
          : (k < 128) ? 0.5f * Wl_ba[(k - 64) * 64 + c]
                      : 0.5f * Wl_aa[(k - 128) * 64 + c];
    } else if (f < 28) {
      int g = f - 24, k = (g >> 1) * 32 + kq, c = (g & 1) * 16 + nidx;
      v = projWA[k * 32 + c];
    } else if (f < 44) {
      int c = (f - 28) * 16 + nidx;
      v = headWA[kq * 256 + c];
    } else if (f < 46) {
      int i2 = (f - 44) * 16 + nidx;
      v = bilW_ba[i2 * 32 + kq];
    } else if (f < 48) {
      int i2 = (f - 46) * 16 + nidx;
      v = bilW_aa[i2 * 32 + kq];
    } else if (f < 64) {
      int g = f - 48, s = g >> 2, nt = g & 3, k = s * 32 + kq, c = nt * 16 + nidx;
      v = (k < 64) ? Wr_ab[k * 64 + c] : Wl_ab[(k - 64) * 64 + c];
    } else if (f < 68) {
      int g = f - 64, k = (g >> 1) * 32 + kq, c = (g & 1) * 16 + nidx;
      v = projWB[k * 32 + c];
    } else if (f < 84) {
      int c = (f - 68) * 16 + nidx;
      v = headWB[kq * 256 + c];
    } else {
      int i2 = (f - 84) * 16 + nidx;
      v = bilW_ab[i2 * 32 + kq];
    }
    dst[j] = f2bf(v);
  }
}

// ---------------- K1: fused multisplit + x0-direct (one launch) ------------------
__global__ void __launch_bounds__(256) k_msx0(
    const int* __restrict__ xA, const int* __restrict__ xB,
    const float* __restrict__ T,
    const float* __restrict__ biasA, const float* __restrict__ biasB,
    u16* __restrict__ x0A, u16* __restrict__ x0B,
    const int* __restrict__ ei_ab, const int* __restrict__ ei_ba,
    const int* __restrict__ ei_aa, int* __restrict__ gcur,
    u32* __restrict__ buckets) {
  __shared__ u32 ebuf2[EPB];   // 16KB sorted staging
  __shared__ int hist[NBKT];   // counts -> ranked-write cursor
  __shared__ int loff[NBKT];   // local exclusive prefix
  __shared__ int delta[NBKT];  // global_off - local_off per bucket
  __shared__ int scanw[256];
  int blk = blockIdx.x;
  int t = threadIdx.x;

  if (blk < MSB) {  // ---- multisplit ----
    int rel = blk / BPR;
    int lb = blk - rel * BPR;
    const int* ei = rel == 0 ? ei_ab : (rel == 1 ? ei_ba : ei_aa);
    int e0 = lb * EPB;
    int n = min(EPB, NE - e0);
    for (int i = t; i < NBKT; i += 256) hist[i] = 0;
    __syncthreads();
    // pass 1: histogram
    for (int i = t; i < n; i += 256) {
      int dstn = ei[NE + e0 + i];
      atomicAdd(&hist[dstn >> 6], 1);
    }
    __syncthreads();
    // exclusive prefix sum hist -> loff (4 entries/thread + scan over 256)
    int base4 = t * 4;
    int s = 0;
#pragma unroll
    for (int k = 0; k < 4; ++k) {
      int idx = base4 + k;
      if (idx < NBKT) s += hist[idx];
    }
    scanw[t] = s;
    __syncthreads();
    for (int off = 1; off < 256; off <<= 1) {
      int v = (t >= off) ? scanw[t - off] : 0;
      __syncthreads();
      scanw[t] += v;
      __syncthreads();
    }
    int run = (t == 0) ? 0 : scanw[t - 1];
#pragma unroll
    for (int k = 0; k < 4; ++k) {
      int idx = base4 + k;
      if (idx < NBKT) {
        loff[idx] = run;
        run += hist[idx];
      }
    }
    __syncthreads();
    // reserve global runs; hist becomes the running ranked-write cursor
    for (int i = t; i < NBKT; i += 256) {
      int c = hist[i];
      if (c > 0) {
        int g = atomicAdd(&gcur[rel * NBKT + i], c);
        delta[i] = g - loff[i];
      }
      hist[i] = loff[i];
    }
    __syncthreads();
    // pass 2a: ranked scatter into LDS, bucket id tagged in bits 22..31
    for (int i = t; i < n; i += 256) {
      int src = ei[e0 + i];
      int dstn = ei[NE + e0 + i];
      int b = dstn >> 6;
      int p = atomicAdd(&hist[b], 1);
      ebuf2[p] = ((u32)b << 22) | ((u32)src << 6) | (u32)(dstn & 63);
    }
    __syncthreads();
    // pass 2b: coalesced copy (consecutive j, same bucket -> consecutive gmem)
    for (int j = t; j < n; j += 256) {
      u32 v = ebuf2[j];
      int b = v >> 22;
      int gpos = delta[b] + j;  // = global_off + local_rank within bucket b
      if (gpos < CAPB)
        buckets[(size_t)(rel * NBKT + b) * CAPB + gpos] = v & 0x3FFFFFu;
    }
    return;
  }

  // ---- x0 direct-gather ----
  int xblk = blk - MSB;  // 0..1563
  int type = xblk >= 782;
  int lb = type ? xblk - 782 : xblk;
  const int* x = type ? xB : xA;
  const float4* Tv = (const float4*)(T + (type ? 16384 : 0));
  const float* bias = type ? biasB : biasA;
  u16* x0 = type ? x0B : x0A;
  const int N = NA;  // NA == NB

  int r = t >> 2, q = t & 3;
  int row = lb * 64 + r;
  bool valid = row < N;
  int arow = valid ? row : (N - 1);
  const int4* xp = (const int4*)(x + arow * 8);
  int4 xa = xp[0], xb = xp[1];
  int bins[8] = {xa.x, xa.y, xa.z, xa.w, xb.x, xb.y, xb.z, xb.w};
  int c0 = q * 16;
  float acc[16];
#pragma unroll
  for (int j = 0; j < 16; ++j) acc[j] = bias[c0 + j];
#pragma unroll
  for (int fd = 0; fd < 8; ++fd) {
    int base = (fd * 32 + bins[fd]) * 16 + q * 4;  // float4 index into T2 row
    float4 v0 = Tv[base], v1 = Tv[base + 1], v2 = Tv[base + 2], v3 = Tv[base + 3];
    acc[0] += v0.x;  acc[1] += v0.y;  acc[2] += v0.z;  acc[3] += v0.w;
    acc[4] += v1.x;  acc[5] += v1.y;  acc[6] += v1.z;  acc[7] += v1.w;
    acc[8] += v2.x;  acc[9] += v2.y;  acc[10] += v2.z; acc[11] += v2.w;
    acc[12] += v3.x; acc[13] += v3.y; acc[14] += v3.z; acc[15] += v3.w;
  }
  if (valid) {
    u32 p[8];
#pragma unroll
    for (int j = 0; j < 8; ++j) {
      u16 lo = f2bf(fmaxf(acc[2 * j], 0.f));
      u16 hi = f2bf(fmaxf(acc[2 * j + 1], 0.f));
      p[j] = (u32)lo | ((u32)hi << 16);
    }
    u32* o = (u32*)(x0 + (size_t)row * 64 + c0);
    *(uint4*)o = *(uint4*)&p[0];
    *((uint4*)o + 1) = *(uint4*)&p[4];
  }
}

// ---------------- K3: per-bucket LDS counting-sort + gather-mean ----------------
__global__ void __launch_bounds__(256) k_meansort_all(
    const u32* __restrict__ buckets, const int* __restrict__ cur,
    const u16* __restrict__ x0A, const u16* __restrict__ x0B,
    u16* __restrict__ mab, u16* __restrict__ mba, u16* __restrict__ maa) {
  __shared__ u32 ebuf[CAPB];
  __shared__ u16 csr[CAPB];
  __shared__ int dcnt[64], doff[64], wcur[64];
  int blk = blockIdx.x;  // 0..3*NBKT-1
  int rel = blk / NBKT;
  int lb = blk - rel * NBKT;
  int t = threadIdx.x;
  const u16* x0 = (rel == 1) ? x0B : x0A;
  u16* out = rel == 0 ? mab : (rel == 1 ? mba : maa);
  int n = min(cur[blk], CAPB);
  const u32* bk = buckets + (size_t)blk * CAPB;
  if (t < 64) dcnt[t] = 0;
  __syncthreads();
  for (int i = t; i < n; i += 256) {
    u32 v = bk[i];
    ebuf[i] = v;
    atomicAdd(&dcnt[v & 63], 1);
  }
  __syncthreads();
  if (t == 0) {
    int s = 0;
#pragma unroll
    for (int d = 0; d < 64; ++d) {
      doff[d] = s;
      wcur[d] = s;
      s += dcnt[d];
    }
  }
  __syncthreads();
  for (int i = t; i < n; i += 256) {
    u32 v = ebuf[i];
    int p = atomicAdd(&wcur[v & 63], 1);
    csr[p] = (u16)(v >> 6);
  }
  __syncthreads();
  int lane = t & 63, w = t >> 6;
  int g = lane >> 4;           // dst sub-group 0..3 within wave
  int dim4 = (lane & 15) * 4;  // this lane's exclusive 4 dims
  int base = lb * 64;
  for (int c = 0; c < 4; ++c) {
    int dloc = w * 16 + c * 4 + g;
    int dstn = base + dloc;
    if (dstn < 50000) {
      int off = doff[dloc], deg = dcnt[dloc];
      float a0 = 0.f, a1 = 0.f, a2 = 0.f, a3 = 0.f;
      int i = 0;
      for (; i + 8 <= deg; i += 8) {
        uint2 v0 = *(const uint2*)(x0 + (size_t)csr[off + i] * 64 + dim4);
        uint2 v1 = *(const uint2*)(x0 + (size_t)csr[off + i + 1] * 64 + dim4);
        uint2 v2 = *(const uint2*)(x0 + (size_t)csr[off + i + 2] * 64 + dim4);
        uint2 v3 = *(const uint2*)(x0 + (size_t)csr[off + i + 3] * 64 + dim4);
        uint2 v4 = *(const uint2*)(x0 + (size_t)csr[off + i + 4] * 64 + dim4);
        uint2 v5 = *(const uint2*)(x0 + (size_t)csr[off + i + 5] * 64 + dim4);
        uint2 v6 = *(const uint2*)(x0 + (size_t)csr[off + i + 6] * 64 + dim4);
        uint2 v7 = *(const uint2*)(x0 + (size_t)csr[off + i + 7] * 64 + dim4);
        a0 += bfl(v0.x) + bfl(v1.x) + bfl(v2.x) + bfl(v3.x) +
              bfl(v4.x) + bfl(v5.x) + bfl(v6.x) + bfl(v7.x);
        a1 += bfh(v0.x) + bfh(v1.x) + bfh(v2.x) + bfh(v3.x) +
              bfh(v4.x) + bfh(v5.x) + bfh(v6.x) + bfh(v7.x);
        a2 += bfl(v0.y) + bfl(v1.y) + bfl(v2.y) + bfl(v3.y) +
              bfl(v4.y) + bfl(v5.y) + bfl(v6.y) + bfl(v7.y);
        a3 += bfh(v0.y) + bfh(v1.y) + bfh(v2.y) + bfh(v3.y) +
              bfh(v4.y) + bfh(v5.y) + bfh(v6.y) + bfh(v7.y);
      }
      for (; i + 4 <= deg; i += 4) {
        uint2 v0 = *(const uint2*)(x0 + (size_t)csr[off + i] * 64 + dim4);
        uint2 v1 = *(const uint2*)(x0 + (size_t)csr[off + i + 1] * 64 + dim4);
        uint2 v2 = *(const uint2*)(x0 + (size_t)csr[off + i + 2] * 64 + dim4);
        uint2 v3 = *(const uint2*)(x0 + (size_t)csr[off + i + 3] * 64 + dim4);
        a0 += bfl(v0.x) + bfl(v1.x) + bfl(v2.x) + bfl(v3.x);
        a1 += bfh(v0.x) + bfh(v1.x) + bfh(v2.x) + bfh(v3.x);
        a2 += bfl(v0.y) + bfl(v1.y) + bfl(v2.y) + bfl(v3.y);
        a3 += bfh(v0.y) + bfh(v1.y) + bfh(v2.y) + bfh(v3.y);
      }
      for (; i < deg; ++i) {
        uint2 v0 = *(const uint2*)(x0 + (size_t)csr[off + i] * 64 + dim4);
        a0 += bfl(v0.x);
        a1 += bfh(v0.x);
        a2 += bfl(v0.y);
        a3 += bfh(v0.y);
      }
      float inv = deg > 0 ? 1.f / (float)deg : 0.f;
      uint2 o;
      o.x = (u32)f2bf(a0 * inv) | ((u32)f2bf(a1 * inv) << 16);
      o.y = (u32)f2bf(a2 * inv) | ((u32)f2bf(a3 * inv) << 16);
      *(uint2*)(out + (size_t)dstn * 64 + dim4) = o;
    }
  }
}

// ---------------- K4: fused MFMA node chain (A and B in one grid) ----------------
template <int NS, int NY>
__device__ __forceinline__ void node_chain(
    const u16* __restrict__ x0, const u16* __restrict__ m1, const u16* __restrict__ m2,
    const u16* __restrict__ frag, int f1, int f2, int fy, int fh,
    const float* __restrict__ hbias, const float* __restrict__ projb,
    const float* __restrict__ headb,
    float* __restrict__ zout, float* __restrict__ flout,
    u16* __restrict__ zbf, u16* __restrict__ y1bf, u16* __restrict__ y2bf,
    int rows0, int N, u16* hld, u16* zld, int lane) {
  int nidx = lane & 15, quad = lane >> 4;
  size_t r0 = (size_t)min(rows0 + nidx, N - 1);
  size_t r1 = (size_t)min(rows0 + 16 + nidx, N - 1);

  f32x4 acc[2][4];
#pragma unroll
  for (int mt = 0; mt < 2; ++mt)
#pragma unroll
    for (int nt = 0; nt < 4; ++nt) acc[mt][nt] = {0.f, 0.f, 0.f, 0.f};
  const u16* mats[3] = {x0, m1, m2};
#pragma unroll
  for (int s = 0; s < NS; ++s) {
    const u16* src = mats[s >> 1];
    int koff = (s & 1) * 32 + quad * 8;
    short8 a0 = *(const short8*)(src + r0 * 64 + koff);
    short8 a1 = *(const short8*)(src + r1 * 64 + koff);
#pragma unroll
    for (int nt = 0; nt < 4; ++nt) {
      short8 b = *(const short8*)(frag + (size_t)(f1 + s * 4 + nt) * 512 + lane * 8);
      acc[0][nt] = MFMA16(a0, b, acc[0][nt]);
      acc[1][nt] = MFMA16(a1, b, acc[1][nt]);
    }
  }
#pragma unroll
  for (int mt = 0; mt < 2; ++mt)
#pragma unroll
    for (int nt = 0; nt < 4; ++nt) {
      int col = nt * 16 + nidx;
      float bb = hbias[col];
#pragma unroll
      for (int r2 = 0; r2 < 4; ++r2)
        hld[(mt * 16 + quad * 4 + r2) * 72 + col] = f2bf(acc[mt][nt][r2] + bb);
    }

  f32x4 zacc[2][2];
#pragma unroll
  for (int mt = 0; mt < 2; ++mt)
#pragma unroll
    for (int nt = 0; nt < 2; ++nt) zacc[mt][nt] = {0.f, 0.f, 0.f, 0.f};
#pragma unroll
  for (int s = 0; s < 2; ++s) {
    short8 a0 = *(const short8*)(hld + nidx * 72 + s * 32 + quad * 8);
    short8 a1 = *(const short8*)(hld + (16 + nidx) * 72 + s * 32 + quad * 8);
#pragma unroll
    for (int nt = 0; nt < 2; ++nt) {
      short8 b = *(const short8*)(frag + (size_t)(f2 + s * 2 + nt) * 512 + lane * 8);
      zacc[0][nt] = MFMA16(a0, b, zacc[0][nt]);
      zacc[1][nt] = MFMA16(a1, b, zacc[1][nt]);
    }
  }
#pragma unroll
  for (int mt = 0; mt < 2; ++mt)
#pragma unroll
    for (int nt = 0; nt < 2; ++nt) {
      int col = nt * 16 + nidx;
      float pb = projb[col];
#pragma unroll
      for (int r2 = 0; r2 < 4; ++r2) {
        int rl = mt * 16 + quad * 4 + r2;
        float zv = fmaxf(zacc[mt][nt][r2] + pb, 0.f);
        zld[rl * 40 + col] = f2bf(zv);
        int grow = rows0 + rl;
        if (grow < N) zout[(size_t)grow * 32 + col] = zv;
      }
    }
  {  // coalesced bf16 z store (2 lanes per row)
    int rl = lane >> 1, hf = lane & 1;
    int grow = rows0 + rl;
    if (grow < N) {
      short8 v0 = *(const short8*)(zld + rl * 40 + hf * 16);
      short8 v1 = *(const short8*)(zld + rl * 40 + hf * 16 + 8);
      *(short8*)(zbf + (size_t)grow * 32 + hf * 16) = v0;
      *(short8*)(zbf + (size_t)grow * 32 + hf * 16 + 8) = v1;
    }
  }

  short8 az0 = *(const short8*)(zld + nidx * 40 + quad * 8);
  short8 az1 = *(const short8*)(zld + (16 + nidx) * 40 + quad * 8);
#pragma unroll
  for (int mat = 0; mat < NY; ++mat) {
    f32x4 ya[2][2];
#pragma unroll
    for (int mt = 0; mt < 2; ++mt)
#pragma unroll
      for (int nt = 0; nt < 2; ++nt) ya[mt][nt] = {0.f, 0.f, 0.f, 0.f};
#pragma unroll
    for (int nt = 0; nt < 2; ++nt) {
      short8 b = *(const short8*)(frag + (size_t)(fy + mat * 2 + nt) * 512 + lane * 8);
      ya[0][nt] = MFMA16(az0, b, ya[0][nt]);
      ya[1][nt] = MFMA16(az1, b, ya[1][nt]);
    }
#pragma unroll
    for (int mt = 0; mt < 2; ++mt)
#pragma unroll
      for (int nt = 0; nt < 2; ++nt)
#pragma unroll
        for (int r2 = 0; r2 < 4; ++r2)
          hld[(mt * 16 + quad * 4 + r2) * 40 + nt * 16 + nidx] = f2bf(ya[mt][nt][r2]);
    u16* yo = mat ? y2bf : y1bf;
    int rl = lane >> 1, hf = lane & 1;
    int grow = rows0 + rl;
    if (grow < N) {
      short8 v0 = *(const short8*)(hld + rl * 40 + hf * 16);
      short8 v1 = *(const short8*)(hld + rl * 40 + hf * 16 + 8);
      *(short8*)(yo + (size_t)grow * 32 + hf * 16) = v0;
      *(short8*)(yo + (size_t)grow * 32 + hf * 16 + 8) = v1;
    }
  }

  for (int chunk = 0; chunk < 4; ++chunk) {
    f32x4 fa[2][4];
#pragma unroll
    for (int mt = 0; mt < 2; ++mt)
#pragma unroll
      for (int nt = 0; nt < 4; ++nt) fa[mt][nt] = {0.f, 0.f, 0.f, 0.f};
#pragma unroll
    for (int nt = 0; nt < 4; ++nt) {
      short8 b = *(const short8*)(frag + (size_t)(fh + chunk * 4 + nt) * 512 + lane * 8);
      fa[0][nt] = MFMA16(az0, b, fa[0][nt]);
      fa[1][nt] = MFMA16(az1, b, fa[1][nt]);
    }
#pragma unroll
    for (int mt = 0; mt < 2; ++mt)
#pragma unroll
      for (int nt = 0; nt < 4; ++nt) {
        int col = chunk * 64 + nt * 16 + nidx;
        float hb = headb[col];
#pragma unroll
        for (int r2 = 0; r2 < 4; ++r2) {
          int grow = rows0 + mt * 16 + quad * 4 + r2;
          if (grow < N) flout[(size_t)grow * 256 + col] = fa[mt][nt][r2] + hb;
        }
      }
  }
}

__global__ void __launch_bounds__(256) k_node(
    const u16* __restrict__ x0A, const u16* __restrict__ mba, const u16* __restrict__ maa,
    const u16* __restrict__ x0B, const u16* __restrict__ mab,
    const u16* __restrict__ frag, const float* __restrict__ bhA,
    const float* __restrict__ bl_ab,
    const float* __restrict__ projbA, const float* __restrict__ headbA,
    const float* __restrict__ projbB, const float* __restrict__ headbB,
    float* __restrict__ zA, float* __restrict__ flA, u16* __restrict__ zAbf,
    u16* __restrict__ ybabf, u16* __restrict__ yaabf,
    float* __restrict__ zB, float* __restrict__ flB, u16* __restrict__ zBbf,
    u16* __restrict__ yabbf) {
  __shared__ u16 lds[4][3584];  // per-wave: h 32x72, z 32x40
  int t = threadIdx.x, lane = t & 63, w = t >> 6;
  u16* hld = &lds[w][0];
  u16* zld = &lds[w][2304];
  int blk = blockIdx.x;
  if (blk < 391) {
    node_chain<6, 2>(x0A, mba, maa, frag, 0, 24, 44, 28, bhA, projbA, headbA,
                     zA, flA, zAbf, ybabf, yaabf, blk * 128 + w * 32, NA, hld, zld, lane);
  } else {
    node_chain<4, 1>(x0B, mab, mab, frag, 48, 64, 84, 68, bl_ab, projbB, headbB,
                     zB, flB, zBbf, yabbf, yabbf, (blk - 391) * 128 + w * 32, NB, hld,
                     zld, lane);
  }
}

// ---------------- K5: bilinear edge scores, ONE RELATION PER LAUNCH --------------
__global__ void k_bil_rel(const int* __restrict__ ei,
                          const u16* __restrict__ zs, const u16* __restrict__ yd,
                          const float* __restrict__ bb, float* __restrict__ so) {
  int le = blockIdx.x * 256 + threadIdx.x;  // grid exactly NE/256
  int si = ei[le], di = ei[NE + le];
  const uint4* zp = (const uint4*)(zs + (size_t)si * 32);
  const uint4* yp = (const uint4*)(yd + (size_t)di * 32);
  float acc = 0.f;
#pragma unroll
  for (int i = 0; i < 4; ++i) {
    uint4 a = zp[i], c = yp[i];
    acc += bfl(a.x) * bfl(c.x) + bfh(a.x) * bfh(c.x);
    acc += bfl(a.y) * bfl(c.y) + bfh(a.y) * bfh(c.y);
    acc += bfl(a.z) * bfl(c.z) + bfh(a.z) * bfh(c.z);
    acc += bfl(a.w) * bfl(c.w) + bfh(a.w) * bfh(c.w);
  }
  so[le] = acc + bb[0];
}

extern "C" void kernel_launch(void* const* d_in, const int* in_sizes, int n_in,
                              void* d_out, int out_size, void* d_ws, size_t ws_size,
                              hipStream_t stream) {
  const int* xA = (const int*)d_in[0];
  const int* xB = (const int*)d_in[1];
  const int* ei_ab = (const int*)d_in[2];
  const int* ei_ba = (const int*)d_in[3];
  const int* ei_aa = (const int*)d_in[4];
  const float* embA = (const float*)d_in[5];
  const float* embB = (const float*)d_in[6];
  const float* preWA = (const float*)d_in[7];
  const float* prebA = (const float*)d_in[8];
  const float* preWB = (const float*)d_in[9];
  const float* prebB = (const float*)d_in[10];
  const float* Wl_ab = (const float*)d_in[11];
  const float* bl_ab = (const float*)d_in[12];
  const float* Wr_ab = (const float*)d_in[13];
  const float* Wl_ba = (const float*)d_in[14];
  const float* bl_ba = (const float*)d_in[15];
  const float* Wr_ba = (const float*)d_in[16];
  const float* Wl_aa = (const float*)d_in[17];
  const float* bl_aa = (const float*)d_in[18];
  const float* Wr_aa = (const float*)d_in[19];
  const float* projWA = (const float*)d_in[20];
  const float* projbA = (const float*)d_in[21];
  const float* projWB = (const float*)d_in[22];
  const float* projbB = (const float*)d_in[23];
  const float* headWA = (const float*)d_in[24];
  const float* headbA = (const float*)d_in[25];
  const float* headWB = (const float*)d_in[26];
  const float* headbB = (const float*)d_in[27];
  const float* bilW_ab = (const float*)d_in[28];
  const float* bilb_ab = (const float*)d_in[29];
  const float* bilW_ba = (const float*)d_in[30];
  const float* bilb_ba = (const float*)d_in[31];
  const float* bilW_aa = (const float*)d_in[32];
  const float* bilb_aa = (const float*)d_in[33];

  float* out = (float*)d_out;
  float* zA = out;                      // 50000*32
  float* zB = out + 1600000;            // 50000*32
  float* flA = out + 3200000;           // 50000*256
  float* flB = out + 16000000;          // 50000*256
  float* s_ab = out + 28800000;
  float* s_ba = out + 29600000;
  float* s_aa = out + 30400000;

  // workspace (byte offsets, all 16B-aligned)
  char* ws = (char*)d_ws;
  float* T = (float*)(ws + 0);            // 131072 B
  u16* x0Abf = (u16*)(ws + 131072);       // 6.4e6 B
  u16* x0Bbf = (u16*)(ws + 6531072);
  u16* mabbf = (u16*)(ws + 12931072);
  u16* mbabf = (u16*)(ws + 19331072);
  u16* maabf = (u16*)(ws + 25731072);
  u16* zAbf = (u16*)(ws + 32131072);      // 3.2e6 B
  u16* zBbf = (u16*)(ws + 35331072);
  u16* yabbf = (u16*)(ws + 38531072);
  u16* ybabf = (u16*)(ws + 41731072);
  u16* yaabf = (u16*)(ws + 44931072);
  int* cur = (int*)(ws + 48131072);       // 3*NBKT ints (dense)
  u16* frag = (u16*)(ws + 48731072);      // 88064 B
  float* bhA = (float*)(ws + 48819136);   // 256 B

  // coarse-bin buckets alias fl_A's d_out region (dead until k_node runs):
  // 3 * 782 * 1536 * 4B = 14.4 MB << 51.2 MB available
  u32* buckets = (u32*)flA;

  // cur zeroing folded into k_pre (blk 150) -- one fewer dispatch
  k_pre<<<151, 256, 0, stream>>>(
      embA, embB, preWA, preWB, T,
      Wr_ba, Wr_aa, Wl_ba, Wl_aa, Wl_ab, Wr_ab, bl_ba, bl_aa,
      projWA, projWB, headWA, headWB, bilW_ba, bilW_aa, bilW_ab,
      frag, bhA, cur);
  k_msx0<<<MSB + 2 * 782, 256, 0, stream>>>(
      xA, xB, T, prebA, prebB, x0Abf, x0Bbf,
      ei_ab, ei_ba, ei_aa, cur, buckets);
  k_meansort_all<<<3 * NBKT, 256, 0, stream>>>(buckets, cur, x0Abf, x0Bbf,
                                               mabbf, mbabf, maabf);
  k_node<<<782, 256, 0, stream>>>(x0Abf, mbabf, maabf, x0Bbf, mabbf, frag, bhA,
                                  bl_ab, projbA, headbA, projbB, headbB,
                                  zA, flA, zAbf, ybabf, yaabf, zB, flB, zBbf, yabbf);
  // ab and aa both gather from zA: run them adjacent so zA stays L2-hot
  k_bil_rel<<<NE / 256, 256, 0, stream>>>(ei_ab, zAbf, yabbf, bilb_ab, s_ab);
  k_bil_rel<<<NE / 256, 256, 0, stream>>>(ei_aa, zAbf, yaabf, bilb_aa, s_aa);
  k_bil_rel<<<NE / 256, 256, 0, stream>>>(ei_ba, zBbf, ybabf, bilb_ba, s_ba);
}